// Round 12
// baseline (201.736 us; speedup 1.0000x reference)
//
#include <hip/hip_runtime.h>

// Problem constants (from reference)
constexpr int B   = 4;
constexpr int CF  = 3;    // feat channels
constexpr int CM  = 21;   // mask channels
constexpr int H   = 128;
constexpr int W   = 128;
constexpr int KS  = 7;
constexpr int PAD = 3;
constexpr int CENTER = (KS * KS) / 2;  // 24
constexpr int NNB = KS * KS - 1;       // 48 neighbors
constexpr int NUM_ITER = 10;

constexpr int TILE = 16;
constexpr int TH   = TILE + 2 * PAD;   // 22 (aff-kernel halo tile)
constexpr int TS   = 24;
constexpr int HW   = H * W;

// fuse-2 geometry
constexpr int IN   = TILE + 4 * PAD;   // 28 input halo tile
constexpr int INS  = 30;               // input LDS row stride (even -> aligned b64 pairs)
constexpr int MD   = 22;               // intermediate (iter t) region
constexpr int MDS  = 24;               // intermediate LDS row stride (even)
constexpr int CPB  = 7;                // channels per block (3 groups)

// ---------------------------------------------------------------------------
// Kernel 1: per-pixel 48-way softmax affinity (validated math).
// NEW: pixel-major layout  aff[((b*H + h)*W + w)*48 + n]  -> 12 dwordx4/px.
// ---------------------------------------------------------------------------
__global__ __launch_bounds__(256) void aff_kernel(const float* __restrict__ feats,
                                                  float* __restrict__ aff) {
    __shared__ float tile[CF][TH][TS];
    const int tx = threadIdx.x, ty = threadIdx.y;
    const int bx = blockIdx.x * TILE, by = blockIdx.y * TILE;
    const int b  = blockIdx.z;
    const int tid = ty * TILE + tx;

    for (int c = 0; c < CF; ++c) {
        const float* src = feats + (size_t)(b * CF + c) * HW;
        for (int idx = tid; idx < TH * TH; idx += 256) {
            const int r  = idx / TH, cc = idx - r * TH;
            const int gh = min(max(by + r  - PAD, 0), H - 1);
            const int gw = min(max(bx + cc - PAD, 0), W - 1);
            tile[c][r][cc] = src[gh * W + gw];
        }
    }
    __syncthreads();

    float q[CF], inv[CF];
    #pragma unroll
    for (int c = 0; c < CF; ++c) {
        const float* tp = &tile[c][ty][tx];
        q[c] = tp[PAD * TS + PAD];
        float s = 0.f, s2 = 0.f;
        #pragma unroll
        for (int i = 0; i < KS; ++i)
            #pragma unroll
            for (int j = 0; j < KS; ++j) {
                if (i == PAD && j == PAD) continue;
                const float v = tp[i * TS + j];
                s += v; s2 += v * v;
            }
        const float mean = s * (1.0f / NNB);
        const float var  = fmaxf(s2 - (float)NNB * mean * mean, 0.f) * (1.0f / (NNB - 1));
        inv[c] = 1.0f / (1e-8f + 0.1f * sqrtf(var));
    }

    float a[NNB];
    float mx = -1e30f;
    #pragma unroll
    for (int i = 0; i < KS; ++i)
        #pragma unroll
        for (int j = 0; j < KS; ++j) {
            const int nn = i * KS + j;
            if (nn == CENTER) continue;
            const int n = (nn < CENTER) ? nn : nn - 1;
            float t = 0.f;
            #pragma unroll
            for (int c = 0; c < CF; ++c)
                t += fabsf(tile[c][ty + i][tx + j] - q[c]) * inv[c];
            a[n] = -t * (1.0f / CF);
            mx = fmaxf(mx, a[n]);
        }
    float ssum = 0.f;
    #pragma unroll
    for (int n = 0; n < NNB; ++n) { a[n] = __expf(a[n] - mx); ssum += a[n]; }
    const float rs = 1.0f / ssum;

    const int h = by + ty, w = bx + tx;
    float* dst = aff + ((size_t)(b * H + h) * W + w) * NNB;
    #pragma unroll
    for (int k = 0; k < 12; ++k)
        *(float4*)(dst + 4 * k) = make_float4(a[4*k] * rs, a[4*k+1] * rs,
                                              a[4*k+2] * rs, a[4*k+3] * rs);
}

// ---------------------------------------------------------------------------
// Kernel 2: TWO fused iterations, pixel-PAIR b64 taps.
// Pass1: 242 pair-threads compute the 22x22 mid region (iter t) into LDS.
// Pass2: 128 pair-threads compute the 16x16 output (iter t+1).
// Window-col union of a pair = 8 words starting even -> 4 aligned ds_read_b64.
// Edge-clamped pairs (col-collapse) take a scalar fallback. 3 blocks/CU.
// ---------------------------------------------------------------------------
__global__ __launch_bounds__(256, 3) void fuse2_kernel(const float* __restrict__ mi,
                                                       const float* __restrict__ aff,
                                                       float* __restrict__ mo) {
    __shared__ float in_t[CPB][IN][INS];   // 23.5 KB
    __shared__ float mid_t[CPB][MD][MDS];  // 14.8 KB

    const int tx = threadIdx.x, ty = threadIdx.y;
    const int tid = ty * TILE + tx;
    const int bx = blockIdx.x * TILE, by = blockIdx.y * TILE;
    const int zz = blockIdx.z;
    const int b  = zz / 3, g = zz % 3;
    const int c0 = g * CPB;

    const float* afb = aff + (size_t)b * HW * NNB;

    // ---- pass-1 pair geometry + aff preload (before staging, overlaps VMEM)
    const bool p1 = tid < 242;
    const int  r  = tid / 11, qp = tid - r * 11;   // mid row, col-pair
    int gh = 0, gw0 = 0, gw1 = 0;
    float4 a0[12], a1[12];
    if (p1) {
        gh  = min(max(by - PAD + r, 0), H - 1);
        gw0 = min(max(bx - PAD + 2 * qp,     0), W - 1);
        gw1 = min(max(bx - PAD + 2 * qp + 1, 0), W - 1);
        const float4* p0 = (const float4*)(afb + ((size_t)gh * W + gw0) * NNB);
        const float4* p1v = (const float4*)(afb + ((size_t)gh * W + gw1) * NNB);
        #pragma unroll
        for (int k = 0; k < 12; ++k) { a0[k] = p0[k]; a1[k] = p1v[k]; }
    }

    // ---- stage 28x28 x 7ch input halo (edge-clamped)
    {
        const float* src = mi + (size_t)(b * CM + c0) * HW;
        for (int s = tid; s < IN * IN; s += 256) {
            const int rr = s / IN, qq = s - rr * IN;
            const int ih = min(max(by - 2 * PAD + rr, 0), H - 1);
            const int iw = min(max(bx - 2 * PAD + qq, 0), W - 1);
            const int go = ih * W + iw;
            #pragma unroll
            for (int c = 0; c < CPB; ++c)
                in_t[c][rr][qq] = src[c * HW + go];
        }
    }
    __syncthreads();

    // ---- pass 1: iteration t on mid 22x22 (pairs)
    if (p1) {
        const int wr  = gh  - by + PAD;    // window top row in in_t
        const int wc0 = gw0 - bx + PAD;    // window left col, px0
        const int wc1 = gw1 - bx + PAD;
        const bool fast = (wc1 == wc0 + 1) && ((wc0 & 1) == 0);
        if (fast) {
            #pragma unroll
            for (int c = 0; c < CPB; ++c) {
                float s0 = 0.f, s1 = 0.f;
                #pragma unroll
                for (int i = 0; i < KS; ++i) {
                    const float* rp = &in_t[c][wr + i][wc0];
                    const float2 d0 = *(const float2*)rp;
                    const float2 d1 = *(const float2*)(rp + 2);
                    const float2 d2 = *(const float2*)(rp + 4);
                    const float2 d3 = *(const float2*)(rp + 6);
                    const float wv[8] = { d0.x, d0.y, d1.x, d1.y, d2.x, d2.y, d3.x, d3.y };
                    #pragma unroll
                    for (int j = 0; j < KS; ++j) {
                        const int nn = i * KS + j;
                        if (nn == CENTER) continue;
                        const int n = (nn < CENTER) ? nn : nn - 1;
                        s0 += ((const float*)&a0[n >> 2])[n & 3] * wv[j];
                        s1 += ((const float*)&a1[n >> 2])[n & 3] * wv[j + 1];
                    }
                }
                *(float2*)&mid_t[c][r][2 * qp] = make_float2(s0, s1);
            }
        } else {
            #pragma unroll
            for (int c = 0; c < CPB; ++c) {
                float s0 = 0.f, s1 = 0.f;
                #pragma unroll
                for (int i = 0; i < KS; ++i)
                    #pragma unroll
                    for (int j = 0; j < KS; ++j) {
                        const int nn = i * KS + j;
                        if (nn == CENTER) continue;
                        const int n = (nn < CENTER) ? nn : nn - 1;
                        s0 += ((const float*)&a0[n >> 2])[n & 3] * in_t[c][wr + i][wc0 + j];
                        s1 += ((const float*)&a1[n >> 2])[n & 3] * in_t[c][wr + i][wc1 + j];
                    }
                *(float2*)&mid_t[c][r][2 * qp] = make_float2(s0, s1);
            }
        }
    }
    __syncthreads();

    // ---- pass 2: iteration t+1 on own 16x16 tile (pairs); aff loaded here
    const bool p2 = tid < 128;
    if (p2) {
        const int trow = tid >> 3, tcol = tid & 7;
        const int oh = by + trow, ow = bx + 2 * tcol;
        float4 b0[12], b1[12];
        const float4* p0 = (const float4*)(afb + ((size_t)oh * W + ow) * NNB);
        const float4* p1v = (const float4*)(afb + ((size_t)oh * W + ow + 1) * NNB);
        #pragma unroll
        for (int k = 0; k < 12; ++k) { b0[k] = p0[k]; b1[k] = p1v[k]; }

        float* dp = mo + (size_t)(b * CM + c0) * HW + (size_t)oh * W + ow;
        #pragma unroll
        for (int c = 0; c < CPB; ++c) {
            float s0 = 0.f, s1 = 0.f;
            #pragma unroll
            for (int i = 0; i < KS; ++i) {
                const float* rp = &mid_t[c][trow + i][2 * tcol];
                const float2 d0 = *(const float2*)rp;
                const float2 d1 = *(const float2*)(rp + 2);
                const float2 d2 = *(const float2*)(rp + 4);
                const float2 d3 = *(const float2*)(rp + 6);
                const float wv[8] = { d0.x, d0.y, d1.x, d1.y, d2.x, d2.y, d3.x, d3.y };
                #pragma unroll
                for (int j = 0; j < KS; ++j) {
                    const int nn = i * KS + j;
                    if (nn == CENTER) continue;
                    const int n = (nn < CENTER) ? nn : nn - 1;
                    s0 += ((const float*)&b0[n >> 2])[n & 3] * wv[j];
                    s1 += ((const float*)&b1[n >> 2])[n & 3] * wv[j + 1];
                }
            }
            *(float2*)(dp + (size_t)c * HW) = make_float2(s0, s1);
        }
    }
}

// ---------------------------------------------------------------------------
extern "C" void kernel_launch(void* const* d_in, const int* in_sizes, int n_in,
                              void* d_out, int out_size, void* d_ws, size_t ws_size,
                              hipStream_t stream) {
    const float* feats = (const float*)d_in[0];
    const float* mask  = (const float*)d_in[1];
    float* out = (float*)d_out;

    float* aff  = (float*)d_ws;                               // 12.58 MB (pixel-major)
    float* buf0 = aff  + (size_t)B * NNB * HW;                // 5.5 MB
    float* buf1 = buf0 + (size_t)B * CM  * HW;                // 5.5 MB

    aff_kernel<<<dim3(W / TILE, H / TILE, B), dim3(TILE, TILE), 0, stream>>>(feats, aff);

    // 5 fused kernels = 10 iterations; last lands in d_out
    dim3 grid(W / TILE, H / TILE, B * 3);
    dim3 blk(TILE, TILE);
    fuse2_kernel<<<grid, blk, 0, stream>>>(mask, aff, buf0);
    fuse2_kernel<<<grid, blk, 0, stream>>>(buf0, aff, buf1);
    fuse2_kernel<<<grid, blk, 0, stream>>>(buf1, aff, buf0);
    fuse2_kernel<<<grid, blk, 0, stream>>>(buf0, aff, buf1);
    fuse2_kernel<<<grid, blk, 0, stream>>>(buf1, aff, out);
}